// Round 19
// baseline (1513.365 us; speedup 1.0000x reference)
//
#include <hip/hip_runtime.h>
#include <stdint.h>

#define N_SEQ 1024
#define N_TOK 4096
#define ATT_SCALE 0.125f

typedef unsigned short u16;
typedef __attribute__((ext_vector_type(8))) short short8;
typedef __attribute__((ext_vector_type(4))) short short4v;
typedef __attribute__((ext_vector_type(4))) float f32x4;

__device__ __forceinline__ u16 f2bf(float f) {
  uint32_t u = __float_as_uint(f);
  u += 0x7fffu + ((u >> 16) & 1u);
  return (u16)(u >> 16);
}

__device__ __forceinline__ float gelu_tanh(float x) {
  float y = 0.79788456f * (x + 0.044715f * x * x * x);
  float ay = fabsf(y);
  float e = __expf(-2.0f * ay);
  float th = (1.0f - e) / (1.0f + e);
  th = __builtin_copysignf(th, y);
  return 0.5f * x * (1.0f + th);
}

__device__ __forceinline__ void gload16(const void* g, void* lds) {
  __builtin_amdgcn_global_load_lds(
      (const __attribute__((address_space(1))) unsigned int*)g,
      (__attribute__((address_space(3))) unsigned int*)lds, 16, 0, 0);
}

// XCD-aware bijective block swizzle (T1): grid total must be divisible by 8.
__device__ __forceinline__ void xcd_swizzle(int& bx, int& by) {
  int gx = gridDim.x, total = gx * gridDim.y;
  int i = blockIdx.y * gx + blockIdx.x;
  int eff = (i & 7) * (total >> 3) + (i >> 3);
  bx = eff % gx;
  by = eff / gx;
}

// ---------------- copy x1 -> d_out ----------------
__global__ void copy_f32_kernel(const float* __restrict__ in, float* __restrict__ out) {
  int i = blockIdx.x * 256 + threadIdx.x;
  ((float4*)out)[i] = ((const float4*)in)[i];
}

// ---------------- weight convert+transpose: fp32 [L][K][NN] -> bf16 [L][NN][K] ----------------
__global__ __launch_bounds__(256) void tconv_kernel(const float* __restrict__ src,
                                                    u16* __restrict__ dst,
                                                    int K, int NN, size_t dstLS) {
  __shared__ u16 tile[64][68];
  int n0 = blockIdx.x * 64, k0 = blockIdx.y * 64, L = blockIdx.z;
  const float* s = src + (size_t)L * K * NN;
  u16* d = dst + (size_t)L * dstLS;
  int t = threadIdx.x;
  int rr = t >> 4, cc = (t & 15) * 4;
#pragma unroll
  for (int ii = 0; ii < 4; ii++) {
    int kl = rr + ii * 16;
    float4 v = *(const float4*)&s[(size_t)(k0 + kl) * NN + n0 + cc];
    tile[cc + 0][kl] = f2bf(v.x);
    tile[cc + 1][kl] = f2bf(v.y);
    tile[cc + 2][kl] = f2bf(v.z);
    tile[cc + 3][kl] = f2bf(v.w);
  }
  __syncthreads();
#pragma unroll
  for (int ii = 0; ii < 4; ii++) {
    int nl = rr + ii * 16;
    short4v o;
    o.x = (short)tile[nl][cc + 0];
    o.y = (short)tile[nl][cc + 1];
    o.z = (short)tile[nl][cc + 2];
    o.w = (short)tile[nl][cc + 3];
    *(short4v*)&d[(size_t)(n0 + nl) * K + k0 + cc] = o;
  }
}

// ---------------- LayerNorm (fp32 in, bf16 out), row = 1024 ----------------
__global__ __launch_bounds__(256) void ln_kernel(const float* __restrict__ x,
                                                 const float* __restrict__ g,
                                                 const float* __restrict__ b,
                                                 u16* __restrict__ out) {
  int row = blockIdx.x;
  const float* xr = x + (size_t)row * 1024;
  int t = threadIdx.x;
  float4 v = *(const float4*)&xr[t * 4];
  float s = v.x + v.y + v.z + v.w;
  float sq = v.x * v.x + v.y * v.y + v.z * v.z + v.w * v.w;
#pragma unroll
  for (int m = 1; m < 64; m <<= 1) {
    s += __shfl_xor(s, m, 64);
    sq += __shfl_xor(sq, m, 64);
  }
  __shared__ float ps[8];
  int w = t >> 6;
  if ((t & 63) == 0) { ps[w] = s; ps[4 + w] = sq; }
  __syncthreads();
  s = ps[0] + ps[1] + ps[2] + ps[3];
  sq = ps[4] + ps[5] + ps[6] + ps[7];
  float mean = s * (1.0f / 1024.0f);
  float var = sq * (1.0f / 1024.0f) - mean * mean;
  float rs = rsqrtf(var + 1e-5f);
  float4 gv = *(const float4*)&g[t * 4];
  float4 bv = *(const float4*)&b[t * 4];
  short4v o;
  o.x = (short)f2bf((v.x - mean) * rs * gv.x + bv.x);
  o.y = (short)f2bf((v.y - mean) * rs * gv.y + bv.y);
  o.z = (short)f2bf((v.z - mean) * rs * gv.z + bv.z);
  o.w = (short)f2bf((v.w - mean) * rs * gv.w + bv.w);
  *(short4v*)&out[(size_t)row * 1024 + t * 4] = o;
}

// ---------------- V transpose: kvb6 V-half [z][4096tok][2048] -> vt [z][64bh][64d][1024n]
__global__ __launch_bounds__(256) void vtrans_kernel(const u16* __restrict__ kvb,
                                                     u16* __restrict__ vt) {
  __shared__ u16 tile[64][72];
  int nt = blockIdx.x, bh = blockIdx.y, z = blockIdx.z;
  int b = bh >> 4, h = bh & 15;
  int t = threadIdx.x;
  int r = t >> 2, c = (t & 3) * 16;
  const u16* src = kvb + (size_t)z * N_TOK * 2048 +
                   (size_t)(b * N_SEQ + nt * 64) * 2048 + 1024 + h * 64;
  short8 v0 = *(const short8*)(src + (size_t)r * 2048 + c);
  short8 v1 = *(const short8*)(src + (size_t)r * 2048 + c + 8);
#pragma unroll
  for (int j = 0; j < 8; j++) {
    tile[r][c + j] = (u16)v0[j];
    tile[r][c + 8 + j] = (u16)v1[j];
  }
  __syncthreads();
  short8 o0, o1;
#pragma unroll
  for (int j = 0; j < 8; j++) {
    o0[j] = (short)tile[c + j][r];
    o1[j] = (short)tile[c + 8 + j][r];
  }
  u16* dst = vt + (size_t)z * 4 * 16 * 64 * 1024 +
             ((size_t)(b * 16 + h) * 64 + r) * 1024 + nt * 64 + c;
  *(short8*)dst = o0;
  *(short8*)(dst + 8) = o1;
}

// ---------------- 2-phase GEMM, z-batchable, XCD-swizzled (wide-grid dispatches) -----
// MODE 0: out bf16. MODE 1: out fp32 = acc + bias + resid. MODE 2: out bf16 = gelu(acc+bias)
template <int BM, int BN, int WM, int WN, int MAXB, int MODE>
__global__ __launch_bounds__(WM * WN * 64, MAXB) void gemmS(const u16* __restrict__ A,
                                                            const u16* __restrict__ Bt,
                                                            u16* __restrict__ outb,
                                                            float* __restrict__ outf,
                                                            const float* __restrict__ bias,
                                                            const float* __restrict__ resid,
                                                            int N, int K,
                                                            size_t zA, size_t zB, size_t zC) {
  constexpr int BK = 64;
  constexpr int NW = WM * WN;
  constexpr int T = NW * 64;
  constexpr int WTM = BM / WM, WTN = BN / WN;
  constexpr int FM = WTM / 16, FN = WTN / 16;
  constexpr int AT = BM * BK, BTL = BN * BK;
  constexpr int LA = AT / 8 / T, LB = BTL / 8 / T;
  __shared__ u16 smem[2 * (AT + BTL)];

  int t = threadIdx.x, lane = t & 63, w = t >> 6;
  int wm = w / WN, wn = w % WN;
  int bx, by;
  xcd_swizzle(bx, by);
  size_t z = blockIdx.z;
  const u16* Ag = A + z * zA + (size_t)(by * BM) * K;
  const u16* Bg = Bt + z * zB + (size_t)(bx * BN) * K;
  f32x4 acc[FM][FN] = {};

  auto stage = [&](int d, int k0) {
    u16* ab = smem + d * (AT + BTL);
    u16* bb = ab + AT;
#pragma unroll
    for (int l = 0; l < LA; l++) {
      int c = (l * NW + w) * 64 + lane;
      int r = c >> 3, s = c & 7;
      gload16(Ag + (size_t)r * K + k0 + ((s ^ (r & 7)) << 3), ab + (l * NW + w) * 512);
    }
#pragma unroll
    for (int l = 0; l < LB; l++) {
      int c = (l * NW + w) * 64 + lane;
      int r = c >> 3, s = c & 7;
      gload16(Bg + (size_t)r * K + k0 + ((s ^ (r & 7)) << 3), bb + (l * NW + w) * 512);
    }
  };

  auto rdA = [&](const u16* ab, int mi, int ks) {
    int rr = wm * WTM + mi * 16 + (lane & 15);
    int j = ks * 4 + (lane >> 4);
    return *(const short8*)&ab[rr * BK + ((j ^ (rr & 7)) << 3)];
  };
  auto rdB = [&](const u16* bb, int ni, int ks) {
    int rr = wn * WTN + ni * 16 + (lane & 15);
    int j = ks * 4 + (lane >> 4);
    return *(const short8*)&bb[rr * BK + ((j ^ (rr & 7)) << 3)];
  };

  const int NT = K / BK;
  stage(0, 0);
  __syncthreads();

  int buf = 0;
  for (int tt = 0; tt < NT; tt++) {
    if (tt + 1 < NT) stage(buf ^ 1, (tt + 1) * BK);
    const u16* ab = smem + buf * (AT + BTL);
    const u16* bb = ab + AT;
    short8 af[2][FM], bfr[2][FN];
#pragma unroll
    for (int ks = 0; ks < 2; ks++) {
#pragma unroll
      for (int mi = 0; mi < FM; mi++) af[ks][mi] = rdA(ab, mi, ks);
#pragma unroll
      for (int ni = 0; ni < FN; ni++) bfr[ks][ni] = rdB(bb, ni, ks);
    }
#pragma unroll
    for (int ks = 0; ks < 2; ks++)
#pragma unroll
      for (int mi = 0; mi < FM; mi++)
#pragma unroll
        for (int ni = 0; ni < FN; ni++)
          acc[mi][ni] = __builtin_amdgcn_mfma_f32_16x16x32_bf16(af[ks][mi], bfr[ks][ni],
                                                                acc[mi][ni], 0, 0, 0);
    __syncthreads();
    buf ^= 1;
  }

  int r0 = by * BM + wm * WTM + ((lane >> 4) << 2);
  int c0 = bx * BN + wn * WTN + (lane & 15);
#pragma unroll
  for (int mi = 0; mi < FM; mi++) {
#pragma unroll
    for (int r = 0; r < 4; r++) {
      size_t row = (size_t)(r0 + mi * 16 + r);
#pragma unroll
      for (int ni = 0; ni < FN; ni++) {
        size_t col = (size_t)(c0 + ni * 16);
        size_t idx = z * zC + row * N + col;
        float val = acc[mi][ni][r];
        if (MODE == 0) {
          outb[idx] = f2bf(val);
        } else if (MODE == 1) {
          outf[idx] = val + bias[col] + resid[idx];
        } else {
          outb[idx] = f2bf(gelu_tanh(val + bias[col]));
        }
      }
    }
  }
}

// ---------------- 4-cluster interleaved GEMM, XCD-swizzled (narrow grid-512 gemms) ----
template <int BM, int BN, int WM, int WN, int MODE>
__global__ __launch_bounds__(WM * WN * 64, 2) void gemm8(const u16* __restrict__ A,
                                                         const u16* __restrict__ Bt,
                                                         u16* __restrict__ outb,
                                                         float* __restrict__ outf,
                                                         const float* __restrict__ bias,
                                                         const float* __restrict__ resid,
                                                         int N, int K) {
  constexpr int BK = 64;
  constexpr int NW = WM * WN;
  constexpr int T = NW * 64;
  constexpr int WTM = BM / WM, WTN = BN / WN;
  constexpr int FM = WTM / 16, FN = WTN / 16, HM = FM / 2;
  constexpr int AT = BM * BK, BTL = BN * BK;
  constexpr int LA = AT / 8 / T, LB = BTL / 8 / T;
  constexpr int LTOT = LA + LB;
  __shared__ u16 smem[2 * (AT + BTL)];

  int t = threadIdx.x, lane = t & 63, w = t >> 6;
  int wm = w / WN, wn = w % WN;
  int bx, by;
  xcd_swizzle(bx, by);
  const u16* Ag = A + (size_t)(by * BM) * K;
  const u16* Bg = Bt + (size_t)(bx * BN) * K;
  f32x4 acc[FM][FN] = {};

  auto stage = [&](int d, int k0) {
    u16* ab = smem + d * (AT + BTL);
    u16* bb = ab + AT;
#pragma unroll
    for (int l = 0; l < LA; l++) {
      int c = (l * NW + w) * 64 + lane;
      int r = c >> 3, s = c & 7;
      gload16(Ag + (size_t)r * K + k0 + ((s ^ (r & 7)) << 3), ab + (l * NW + w) * 512);
    }
#pragma unroll
    for (int l = 0; l < LB; l++) {
      int c = (l * NW + w) * 64 + lane;
      int r = c >> 3, s = c & 7;
      gload16(Bg + (size_t)r * K + k0 + ((s ^ (r & 7)) << 3), bb + (l * NW + w) * 512);
    }
  };

  auto rdA = [&](const u16* ab, int mi, int ks) {
    int rr = wm * WTM + mi * 16 + (lane & 15);
    int j = ks * 4 + (lane >> 4);
    return *(const short8*)&ab[rr * BK + ((j ^ (rr & 7)) << 3)];
  };
  auto rdB = [&](const u16* bb, int ni, int ks) {
    int rr = wn * WTN + ni * 16 + (lane & 15);
    int j = ks * 4 + (lane >> 4);
    return *(const short8*)&bb[rr * BK + ((j ^ (rr & 7)) << 3)];
  };

  const int NT = K / BK;
  stage(0, 0);
  stage(1, BK);
  __builtin_amdgcn_sched_barrier(0);

  int buf = 0;
  for (int tt = 0; tt < NT; tt++) {
    asm volatile("s_waitcnt vmcnt(%0)" ::"n"(LTOT) : "memory");
    __builtin_amdgcn_s_barrier();
    __builtin_amdgcn_sched_barrier(0);
    const u16* ab = smem + buf * (AT + BTL);
    const u16* bb = ab + AT;
    short8 b0[FN], a0lo[HM], a0hi[HM], b1[FN], a1lo[HM], a1hi[HM];
#pragma unroll
    for (int n = 0; n < FN; n++) b0[n] = rdB(bb, n, 0);
#pragma unroll
    for (int m = 0; m < HM; m++) a0lo[m] = rdA(ab, m, 0);
#pragma unroll
    for (int m = 0; m < HM; m++) a0hi[m] = rdA(ab, HM + m, 0);
    asm volatile("s_waitcnt lgkmcnt(%0)" ::"n"(HM) : "memory");
    __builtin_amdgcn_sched_barrier(0);
#pragma unroll
    for (int n = 0; n < FN; n++) b1[n] = rdB(bb, n, 1);
#pragma unroll
    for (int m = 0; m < HM; m++) a1lo[m] = rdA(ab, m, 1);
    __builtin_amdgcn_s_setprio(1);
#pragma unroll
    for (int m = 0; m < HM; m++)
#pragma unroll
      for (int n = 0; n < FN; n++)
        acc[m][n] = __builtin_amdgcn_mfma_f32_16x16x32_bf16(a0lo[m], b0[n], acc[m][n], 0, 0, 0);
    __builtin_amdgcn_s_setprio(0);
    asm volatile("s_waitcnt lgkmcnt(%0)" ::"n"(FN + HM) : "memory");
    __builtin_amdgcn_sched_barrier(0);
#pragma unroll
    for (int m = 0; m < HM; m++) a1hi[m] = rdA(ab, HM + m, 1);
    __builtin_amdgcn_s_setprio(1);
#pragma unroll
    for (int m = 0; m < HM; m++)
#pragma unroll
      for (int n = 0; n < FN; n++)
        acc[HM + m][n] = __builtin_amdgcn_mfma_f32_16x16x32_bf16(a0hi[m], b0[n], acc[HM + m][n], 0, 0, 0);
    __builtin_amdgcn_s_setprio(0);
    asm volatile("s_waitcnt lgkmcnt(%0)" ::"n"(HM) : "memory");
    __builtin_amdgcn_sched_barrier(0);
    __builtin_amdgcn_s_setprio(1);
#pragma unroll
    for (int m = 0; m < HM; m++)
#pragma unroll
      for (int n = 0; n < FN; n++)
        acc[m][n] = __builtin_amdgcn_mfma_f32_16x16x32_bf16(a1lo[m], b1[n], acc[m][n], 0, 0, 0);
    __builtin_amdgcn_s_setprio(0);
    asm volatile("s_waitcnt lgkmcnt(0)" ::: "memory");
    __builtin_amdgcn_sched_barrier(0);
    __builtin_amdgcn_s_barrier();
    __builtin_amdgcn_sched_barrier(0);
    stage(buf, ((tt + 2) % NT) * BK);
    __builtin_amdgcn_sched_barrier(0);
    __builtin_amdgcn_s_setprio(1);
#pragma unroll
    for (int m = 0; m < HM; m++)
#pragma unroll
      for (int n = 0; n < FN; n++)
        acc[HM + m][n] = __builtin_amdgcn_mfma_f32_16x16x32_bf16(a1hi[m], b1[n], acc[HM + m][n], 0, 0, 0);
    __builtin_amdgcn_s_setprio(0);
    buf ^= 1;
  }

  int r0 = by * BM + wm * WTM + ((lane >> 4) << 2);
  int c0 = bx * BN + wn * WTN + (lane & 15);
#pragma unroll
  for (int mi = 0; mi < FM; mi++) {
#pragma unroll
    for (int r = 0; r < 4; r++) {
      size_t row = (size_t)(r0 + mi * 16 + r);
#pragma unroll
      for (int ni = 0; ni < FN; ni++) {
        size_t col = (size_t)(c0 + ni * 16);
        size_t idx = row * N + col;
        float val = acc[mi][ni][r];
        if (MODE == 0) {
          outb[idx] = f2bf(val);
        } else if (MODE == 1) {
          outf[idx] = val + bias[col] + resid[idx];
        } else {
          outb[idx] = f2bf(gelu_tanh(val + bias[col]));
        }
      }
    }
  }
}

// ---------------- flash attention v4: QBLK=128, 8 waves, K/V via global_load_lds ------
// K/V staged direct-to-LDS (no VGPR roundtrip), 2-slot double buffer, gemm8 ledger:
// prologue stages tiles 0,1; per iter {vmcnt(2) -> barrier -> compute(slot) -> barrier
// -> stage((t+2)&15 -> slot)} (wrapped tail keeps count exact). Swizzle preserved via
// linear dest chunk t + pre-swizzled source chunk (both-sides identity, read unchanged).
__global__ __launch_bounds__(512, 2) void attn_kernel(const u16* __restrict__ qb,
                                                      const u16* __restrict__ kvb,
                                                      const u16* __restrict__ vtb,
                                                      u16* __restrict__ ob) {
  int qt = blockIdx.x, bh = blockIdx.y;
  int b = bh >> 4, h = bh & 15;
  int t = threadIdx.x, lane = t & 63, w = t >> 6;  // 8 waves
  __shared__ u16 Qs[128 * 64];
  __shared__ u16 Ks[2][64 * 64];
  __shared__ u16 Vt[2][64 * 64];
  __shared__ u16 Ps[8][16 * 64];

  const u16* qbase = qb + (size_t)b * N_SEQ * 1024 + h * 64;
  const u16* kbase = kvb + (size_t)b * N_SEQ * 2048 + h * 64;
  const u16* vtbase = vtb + ((size_t)(b * 16 + h) * 64) * 1024;
  u16* obase = ob + (size_t)b * N_SEQ * 1024 + h * 64;

  {  // Q: 128 rows x 64 cols, 2 short8 per thread
    int r = t >> 2, c = (t & 3) * 16;
    const u16* src = qbase + (size_t)(qt * 128 + r) * 1024 + c;
    *(short8*)&Qs[r * 64 + c] = *(const short8*)src;
    *(short8*)&Qs[r * 64 + c + 8] = *(const short8*)(src + 8);
  }
  // K/V stage via gload16: thread t covers 16B chunk t of the 64x64 tile.
  // dest = tile + t*8 elems (linear, satisfies wave-uniform-base + lane*16 rule);
  // source chunk pre-swizzled: jj ^ (kr & 7)  ->  LDS[kr][c] = src[c ^ (kr&7)].
  int kr = t >> 3, jj = t & 7;
  int sc = (jj ^ (kr & 7)) * 8;  // pre-swizzled source column (elements)
  auto stageKV = [&](int slot, int kt) {
    gload16(kbase + (size_t)(kt * 64 + kr) * 2048 + sc, &Ks[slot][t * 8]);
    gload16(vtbase + (size_t)kr * 1024 + kt * 64 + sc, &Vt[slot][t * 8]);
  };
  stageKV(0, 0);
  stageKV(1, 1);
  __builtin_amdgcn_sched_barrier(0);
  __syncthreads();
  short8 qa0 = *(const short8*)&Qs[(w * 16 + (lane & 15)) * 64 + (lane >> 4) * 8];
  short8 qa1 = *(const short8*)&Qs[(w * 16 + (lane & 15)) * 64 + 32 + (lane >> 4) * 8];

  f32x4 o[4] = {};
  float m_r[4] = {-1e30f, -1e30f, -1e30f, -1e30f};
  float l_r[4] = {0.0f, 0.0f, 0.0f, 0.0f};

  for (int kt = 0; kt < 16; kt++) {
    int sl = kt & 1;
    asm volatile("s_waitcnt vmcnt(2)" ::: "memory");  // tile kt landed (2 newest = kt+1)
    __builtin_amdgcn_s_barrier();
    __builtin_amdgcn_sched_barrier(0);

    f32x4 s[4] = {};
#pragma unroll
    for (int kb = 0; kb < 4; kb++) {
      int key = kb * 16 + (lane & 15);
      int j2 = lane >> 4;
      short8 k0 = *(const short8*)&Ks[sl][key * 64 + ((j2 ^ (key & 7)) << 3)];
      short8 k1 = *(const short8*)&Ks[sl][key * 64 + (((4 + j2) ^ (key & 7)) << 3)];
      s[kb] = __builtin_amdgcn_mfma_f32_16x16x32_bf16(qa0, k0, s[kb], 0, 0, 0);
      s[kb] = __builtin_amdgcn_mfma_f32_16x16x32_bf16(qa1, k1, s[kb], 0, 0, 0);
    }
    float fac[4], rowsum[4];
#pragma unroll
    for (int rr = 0; rr < 4; rr++) {
      float a = fmaxf(fmaxf(s[0][rr], s[1][rr]), fmaxf(s[2][rr], s[3][rr])) * ATT_SCALE;
      a = fmaxf(a, __shfl_xor(a, 1, 64));
      a = fmaxf(a, __shfl_xor(a, 2, 64));
      a = fmaxf(a, __shfl_xor(a, 4, 64));
      a = fmaxf(a, __shfl_xor(a, 8, 64));
      float mn = fmaxf(m_r[rr], a);
      fac[rr] = __expf(m_r[rr] - mn);
      m_r[rr] = mn;
      rowsum[rr] = 0.0f;
    }
#pragma unroll
    for (int kb = 0; kb < 4; kb++) {
      int chunk = 2 * kb + ((lane & 15) >> 3);
#pragma unroll
      for (int rr = 0; rr < 4; rr++) {
        float p = __expf(s[kb][rr] * ATT_SCALE - m_r[rr]);
        rowsum[rr] += p;
        int row = (lane >> 4) * 4 + rr;
        Ps[w][row * 64 + ((chunk ^ (row & 7)) << 3) + (lane & 7)] = f2bf(p);
      }
    }
#pragma unroll
    for (int rr = 0; rr < 4; rr++) {
      float rs = rowsum[rr];
      rs += __shfl_xor(rs, 1, 64);
      rs += __shfl_xor(rs, 2, 64);
      rs += __shfl_xor(rs, 4, 64);
      rs += __shfl_xor(rs, 8, 64);
      l_r[rr] = l_r[rr] * fac[rr] + rs;
      o[0][rr] *= fac[rr];
      o[1][rr] *= fac[rr];
      o[2][rr] *= fac[rr];
      o[3][rr] *= fac[rr];
    }
#pragma unroll
    for (int ks = 0; ks < 2; ks++) {
      int rowp = lane & 15;
      int j2 = 4 * ks + (lane >> 4);
      short8 pf = *(const short8*)&Ps[w][rowp * 64 + ((j2 ^ (rowp & 7)) << 3)];
#pragma unroll
      for (int db = 0; db < 4; db++) {
        int row = db * 16 + (lane & 15);
        short8 vf = *(const short8*)&Vt[sl][row * 64 + ((j2 ^ (row & 7)) << 3)];
        o[db] = __builtin_amdgcn_mfma_f32_16x16x32_bf16(pf, vf, o[db], 0, 0, 0);
      }
    }
    __builtin_amdgcn_s_barrier();  // all waves done reading slot sl
    __builtin_amdgcn_sched_barrier(0);
    stageKV(sl, (kt + 2) & 15);  // uniform ledger: wrapped tail (tiles 0,1 refetched)
    __builtin_amdgcn_sched_barrier(0);
  }
#pragma unroll
  for (int rr = 0; rr < 4; rr++) {
    float inv = 1.0f / l_r[rr];
    size_t row = (size_t)(qt * 128 + w * 16 + (lane >> 4) * 4 + rr);
#pragma unroll
    for (int db = 0; db < 4; db++)
      obase[row * 1024 + db * 16 + (lane & 15)] = f2bf(o[db][rr] * inv);
  }
}

extern "C" void kernel_launch(void* const* d_in, const int* in_sizes, int n_in,
                              void* d_out, int out_size, void* d_ws, size_t ws_size,
                              hipStream_t stream) {
  const float* x1 = (const float*)d_in[0];
  const float* x2 = (const float*)d_in[1];
  const float* ln1_g = (const float*)d_in[2];
  const float* ln1_b = (const float*)d_in[3];
  const float* wq = (const float*)d_in[4];
  const float* wk = (const float*)d_in[5];
  const float* wv = (const float*)d_in[6];
  const float* wo = (const float*)d_in[7];
  const float* bo = (const float*)d_in[8];
  const float* ln2_g = (const float*)d_in[9];
  const float* ln2_b = (const float*)d_in[10];
  const float* w1 = (const float*)d_in[11];
  const float* b1 = (const float*)d_in[12];
  const float* w2 = (const float*)d_in[13];
  const float* b2 = (const float*)d_in[14];
  float* xout = (float*)d_out;

  u16* p = (u16*)d_ws;
  u16* wqt = p;   p += (size_t)6 * 1024 * 1024;
  u16* kvt = p;   p += (size_t)6 * 2048 * 1024;
  u16* wot = p;   p += (size_t)6 * 1024 * 1024;
  u16* w1t = p;   p += (size_t)6 * 4096 * 1024;
  u16* w2t = p;   p += (size_t)6 * 1024 * 4096;
  u16* n1 = p;    p += (size_t)N_TOK * 1024;
  u16* n2all = p; p += (size_t)6 * N_TOK * 1024;  // later reused as vtb6 (same size)
  u16* qbuf = p;  p += (size_t)N_TOK * 1024;
  u16* kvb6 = p;  p += (size_t)6 * N_TOK * 2048;
  u16* ao = p;    p += (size_t)N_TOK * 1024;
  u16* hid = p;   p += (size_t)N_TOK * 4096;
  u16* vtb6 = n2all;  // alias: n2all dead after the KV gemm

  dim3 blk(256);
  tconv_kernel<<<dim3(16, 16, 6), blk, 0, stream>>>(wq, wqt, 1024, 1024, (size_t)1024 * 1024);
  tconv_kernel<<<dim3(16, 16, 6), blk, 0, stream>>>(wk, kvt, 1024, 1024, (size_t)2048 * 1024);
  tconv_kernel<<<dim3(16, 16, 6), blk, 0, stream>>>(wv, kvt + (size_t)1024 * 1024, 1024, 1024, (size_t)2048 * 1024);
  tconv_kernel<<<dim3(16, 16, 6), blk, 0, stream>>>(wo, wot, 1024, 1024, (size_t)1024 * 1024);
  tconv_kernel<<<dim3(64, 16, 6), blk, 0, stream>>>(w1, w1t, 1024, 4096, (size_t)4096 * 1024);
  tconv_kernel<<<dim3(16, 64, 6), blk, 0, stream>>>(w2, w2t, 4096, 1024, (size_t)1024 * 4096);
  copy_f32_kernel<<<4096, blk, 0, stream>>>(x1, xout);

  // x2 layer-invariant: 6 LN upfront, one z-batched KV dispatch, V^T materialization.
  for (int i = 0; i < 6; i++)
    ln_kernel<<<N_TOK, blk, 0, stream>>>(x2, ln1_g + i * 1024, ln1_b + i * 1024,
                                         n2all + (size_t)i * N_TOK * 1024);
  gemmS<64, 128, 2, 2, 3, 0><<<dim3(16, 64, 6), blk, 0, stream>>>(
      n2all, kvt, kvb6, nullptr, nullptr, nullptr, 2048, 1024,
      (size_t)N_TOK * 1024, (size_t)2048 * 1024, (size_t)N_TOK * 2048);
  vtrans_kernel<<<dim3(16, 64, 6), blk, 0, stream>>>(kvb6, vtb6);

  for (int i = 0; i < 6; i++) {
    ln_kernel<<<N_TOK, blk, 0, stream>>>(xout, ln1_g + i * 1024, ln1_b + i * 1024, n1);
    // q: gemm8 128x64, grid 512
    gemm8<128, 64, 2, 2, 0><<<dim3(16, 32), blk, 0, stream>>>(
        n1, wqt + (size_t)i * 1024 * 1024, qbuf, nullptr, nullptr, nullptr, 1024, 1024);
    // attn v4: QBLK=128, grid (8,64), 512 threads, gload16 K/V double-buffer
    attn_kernel<<<dim3(8, 64), dim3(512), 0, stream>>>(
        qbuf, kvb6 + (size_t)i * N_TOK * 2048, vtb6 + (size_t)i * 4 * 16 * 64 * 1024, ao);
    // wo + bias + residual
    gemm8<128, 64, 2, 2, 1><<<dim3(16, 32), blk, 0, stream>>>(
        ao, wot + (size_t)i * 1024 * 1024, nullptr, xout, bo + i * 1024, xout, 1024, 1024);
    ln_kernel<<<N_TOK, blk, 0, stream>>>(xout, ln2_g + i * 1024, ln2_b + i * 1024, n1);
    // ff1 + gelu: gemmS 64x128 grid (32,64)=2048
    gemmS<64, 128, 2, 2, 3, 2><<<dim3(32, 64), blk, 0, stream>>>(
        n1, w1t + (size_t)i * 4096 * 1024, hid, nullptr, b1 + i * 4096, nullptr, 4096, 1024, 0, 0, 0);
    // ff2 + bias + residual: gemm8 128x64, K=4096
    gemm8<128, 64, 2, 2, 1><<<dim3(16, 32), blk, 0, stream>>>(
        hid, w2t + (size_t)i * 1024 * 4096, nullptr, xout, b2 + i * 1024, xout, 1024, 4096);
  }
}

// Round 20
// 1481.085 us; speedup vs baseline: 1.0218x; 1.0218x over previous
//
#include <hip/hip_runtime.h>
#include <stdint.h>

#define N_SEQ 1024
#define N_TOK 4096
#define ATT_SCALE 0.125f

typedef unsigned short u16;
typedef __attribute__((ext_vector_type(8))) short short8;
typedef __attribute__((ext_vector_type(4))) short short4v;
typedef __attribute__((ext_vector_type(4))) float f32x4;

__device__ __forceinline__ u16 f2bf(float f) {
  uint32_t u = __float_as_uint(f);
  u += 0x7fffu + ((u >> 16) & 1u);
  return (u16)(u >> 16);
}

__device__ __forceinline__ float gelu_tanh(float x) {
  float y = 0.79788456f * (x + 0.044715f * x * x * x);
  float ay = fabsf(y);
  float e = __expf(-2.0f * ay);
  float th = (1.0f - e) / (1.0f + e);
  th = __builtin_copysignf(th, y);
  return 0.5f * x * (1.0f + th);
}

__device__ __forceinline__ void gload16(const void* g, void* lds) {
  __builtin_amdgcn_global_load_lds(
      (const __attribute__((address_space(1))) unsigned int*)g,
      (__attribute__((address_space(3))) unsigned int*)lds, 16, 0, 0);
}

// XCD-aware bijective block swizzle (T1): grid total must be divisible by 8.
__device__ __forceinline__ void xcd_swizzle(int& bx, int& by) {
  int gx = gridDim.x, total = gx * gridDim.y;
  int i = blockIdx.y * gx + blockIdx.x;
  int eff = (i & 7) * (total >> 3) + (i >> 3);
  bx = eff % gx;
  by = eff / gx;
}

// ---------------- copy x1 -> d_out ----------------
__global__ void copy_f32_kernel(const float* __restrict__ in, float* __restrict__ out) {
  int i = blockIdx.x * 256 + threadIdx.x;
  ((float4*)out)[i] = ((const float4*)in)[i];
}

// ---------------- weight convert+transpose: fp32 [L][K][NN] -> bf16 [L][NN][K] ----------------
__global__ __launch_bounds__(256) void tconv_kernel(const float* __restrict__ src,
                                                    u16* __restrict__ dst,
                                                    int K, int NN, size_t dstLS) {
  __shared__ u16 tile[64][68];
  int n0 = blockIdx.x * 64, k0 = blockIdx.y * 64, L = blockIdx.z;
  const float* s = src + (size_t)L * K * NN;
  u16* d = dst + (size_t)L * dstLS;
  int t = threadIdx.x;
  int rr = t >> 4, cc = (t & 15) * 4;
#pragma unroll
  for (int ii = 0; ii < 4; ii++) {
    int kl = rr + ii * 16;
    float4 v = *(const float4*)&s[(size_t)(k0 + kl) * NN + n0 + cc];
    tile[cc + 0][kl] = f2bf(v.x);
    tile[cc + 1][kl] = f2bf(v.y);
    tile[cc + 2][kl] = f2bf(v.z);
    tile[cc + 3][kl] = f2bf(v.w);
  }
  __syncthreads();
#pragma unroll
  for (int ii = 0; ii < 4; ii++) {
    int nl = rr + ii * 16;
    short4v o;
    o.x = (short)tile[nl][cc + 0];
    o.y = (short)tile[nl][cc + 1];
    o.z = (short)tile[nl][cc + 2];
    o.w = (short)tile[nl][cc + 3];
    *(short4v*)&d[(size_t)(n0 + nl) * K + k0 + cc] = o;
  }
}

// ---------------- LayerNorm (fp32 in, bf16 out), row = 1024 ----------------
__global__ __launch_bounds__(256) void ln_kernel(const float* __restrict__ x,
                                                 const float* __restrict__ g,
                                                 const float* __restrict__ b,
                                                 u16* __restrict__ out) {
  int row = blockIdx.x;
  const float* xr = x + (size_t)row * 1024;
  int t = threadIdx.x;
  float4 v = *(const float4*)&xr[t * 4];
  float s = v.x + v.y + v.z + v.w;
  float sq = v.x * v.x + v.y * v.y + v.z * v.z + v.w * v.w;
#pragma unroll
  for (int m = 1; m < 64; m <<= 1) {
    s += __shfl_xor(s, m, 64);
    sq += __shfl_xor(sq, m, 64);
  }
  __shared__ float ps[8];
  int w = t >> 6;
  if ((t & 63) == 0) { ps[w] = s; ps[4 + w] = sq; }
  __syncthreads();
  s = ps[0] + ps[1] + ps[2] + ps[3];
  sq = ps[4] + ps[5] + ps[6] + ps[7];
  float mean = s * (1.0f / 1024.0f);
  float var = sq * (1.0f / 1024.0f) - mean * mean;
  float rs = rsqrtf(var + 1e-5f);
  float4 gv = *(const float4*)&g[t * 4];
  float4 bv = *(const float4*)&b[t * 4];
  short4v o;
  o.x = (short)f2bf((v.x - mean) * rs * gv.x + bv.x);
  o.y = (short)f2bf((v.y - mean) * rs * gv.y + bv.y);
  o.z = (short)f2bf((v.z - mean) * rs * gv.z + bv.z);
  o.w = (short)f2bf((v.w - mean) * rs * gv.w + bv.w);
  *(short4v*)&out[(size_t)row * 1024 + t * 4] = o;
}

// ---------------- V transpose: kvb6 V-half [z][4096tok][2048] -> vt [z][64bh][64d][1024n]
__global__ __launch_bounds__(256) void vtrans_kernel(const u16* __restrict__ kvb,
                                                     u16* __restrict__ vt) {
  __shared__ u16 tile[64][72];
  int nt = blockIdx.x, bh = blockIdx.y, z = blockIdx.z;
  int b = bh >> 4, h = bh & 15;
  int t = threadIdx.x;
  int r = t >> 2, c = (t & 3) * 16;
  const u16* src = kvb + (size_t)z * N_TOK * 2048 +
                   (size_t)(b * N_SEQ + nt * 64) * 2048 + 1024 + h * 64;
  short8 v0 = *(const short8*)(src + (size_t)r * 2048 + c);
  short8 v1 = *(const short8*)(src + (size_t)r * 2048 + c + 8);
#pragma unroll
  for (int j = 0; j < 8; j++) {
    tile[r][c + j] = (u16)v0[j];
    tile[r][c + 8 + j] = (u16)v1[j];
  }
  __syncthreads();
  short8 o0, o1;
#pragma unroll
  for (int j = 0; j < 8; j++) {
    o0[j] = (short)tile[c + j][r];
    o1[j] = (short)tile[c + 8 + j][r];
  }
  u16* dst = vt + (size_t)z * 4 * 16 * 64 * 1024 +
             ((size_t)(b * 16 + h) * 64 + r) * 1024 + nt * 64 + c;
  *(short8*)dst = o0;
  *(short8*)(dst + 8) = o1;
}

// ---------------- 2-phase GEMM, z-batchable, XCD-swizzled (wide-grid dispatches) -----
// MODE 0: out bf16. MODE 1: out fp32 = acc + bias + resid. MODE 2: out bf16 = gelu(acc+bias)
template <int BM, int BN, int WM, int WN, int MAXB, int MODE>
__global__ __launch_bounds__(WM * WN * 64, MAXB) void gemmS(const u16* __restrict__ A,
                                                            const u16* __restrict__ Bt,
                                                            u16* __restrict__ outb,
                                                            float* __restrict__ outf,
                                                            const float* __restrict__ bias,
                                                            const float* __restrict__ resid,
                                                            int N, int K,
                                                            size_t zA, size_t zB, size_t zC) {
  constexpr int BK = 64;
  constexpr int NW = WM * WN;
  constexpr int T = NW * 64;
  constexpr int WTM = BM / WM, WTN = BN / WN;
  constexpr int FM = WTM / 16, FN = WTN / 16;
  constexpr int AT = BM * BK, BTL = BN * BK;
  constexpr int LA = AT / 8 / T, LB = BTL / 8 / T;
  __shared__ u16 smem[2 * (AT + BTL)];

  int t = threadIdx.x, lane = t & 63, w = t >> 6;
  int wm = w / WN, wn = w % WN;
  int bx, by;
  xcd_swizzle(bx, by);
  size_t z = blockIdx.z;
  const u16* Ag = A + z * zA + (size_t)(by * BM) * K;
  const u16* Bg = Bt + z * zB + (size_t)(bx * BN) * K;
  f32x4 acc[FM][FN] = {};

  auto stage = [&](int d, int k0) {
    u16* ab = smem + d * (AT + BTL);
    u16* bb = ab + AT;
#pragma unroll
    for (int l = 0; l < LA; l++) {
      int c = (l * NW + w) * 64 + lane;
      int r = c >> 3, s = c & 7;
      gload16(Ag + (size_t)r * K + k0 + ((s ^ (r & 7)) << 3), ab + (l * NW + w) * 512);
    }
#pragma unroll
    for (int l = 0; l < LB; l++) {
      int c = (l * NW + w) * 64 + lane;
      int r = c >> 3, s = c & 7;
      gload16(Bg + (size_t)r * K + k0 + ((s ^ (r & 7)) << 3), bb + (l * NW + w) * 512);
    }
  };

  auto rdA = [&](const u16* ab, int mi, int ks) {
    int rr = wm * WTM + mi * 16 + (lane & 15);
    int j = ks * 4 + (lane >> 4);
    return *(const short8*)&ab[rr * BK + ((j ^ (rr & 7)) << 3)];
  };
  auto rdB = [&](const u16* bb, int ni, int ks) {
    int rr = wn * WTN + ni * 16 + (lane & 15);
    int j = ks * 4 + (lane >> 4);
    return *(const short8*)&bb[rr * BK + ((j ^ (rr & 7)) << 3)];
  };

  const int NT = K / BK;
  stage(0, 0);
  __syncthreads();

  int buf = 0;
  for (int tt = 0; tt < NT; tt++) {
    if (tt + 1 < NT) stage(buf ^ 1, (tt + 1) * BK);
    const u16* ab = smem + buf * (AT + BTL);
    const u16* bb = ab + AT;
    short8 af[2][FM], bfr[2][FN];
#pragma unroll
    for (int ks = 0; ks < 2; ks++) {
#pragma unroll
      for (int mi = 0; mi < FM; mi++) af[ks][mi] = rdA(ab, mi, ks);
#pragma unroll
      for (int ni = 0; ni < FN; ni++) bfr[ks][ni] = rdB(bb, ni, ks);
    }
#pragma unroll
    for (int ks = 0; ks < 2; ks++)
#pragma unroll
      for (int mi = 0; mi < FM; mi++)
#pragma unroll
        for (int ni = 0; ni < FN; ni++)
          acc[mi][ni] = __builtin_amdgcn_mfma_f32_16x16x32_bf16(af[ks][mi], bfr[ks][ni],
                                                                acc[mi][ni], 0, 0, 0);
    __syncthreads();
    buf ^= 1;
  }

  int r0 = by * BM + wm * WTM + ((lane >> 4) << 2);
  int c0 = bx * BN + wn * WTN + (lane & 15);
#pragma unroll
  for (int mi = 0; mi < FM; mi++) {
#pragma unroll
    for (int r = 0; r < 4; r++) {
      size_t row = (size_t)(r0 + mi * 16 + r);
#pragma unroll
      for (int ni = 0; ni < FN; ni++) {
        size_t col = (size_t)(c0 + ni * 16);
        size_t idx = z * zC + row * N + col;
        float val = acc[mi][ni][r];
        if (MODE == 0) {
          outb[idx] = f2bf(val);
        } else if (MODE == 1) {
          outf[idx] = val + bias[col] + resid[idx];
        } else {
          outb[idx] = f2bf(gelu_tanh(val + bias[col]));
        }
      }
    }
  }
}

// ---------------- 4-cluster interleaved GEMM, XCD-swizzled (narrow grid-512 gemms) ----
template <int BM, int BN, int WM, int WN, int MODE>
__global__ __launch_bounds__(WM * WN * 64, 2) void gemm8(const u16* __restrict__ A,
                                                         const u16* __restrict__ Bt,
                                                         u16* __restrict__ outb,
                                                         float* __restrict__ outf,
                                                         const float* __restrict__ bias,
                                                         const float* __restrict__ resid,
                                                         int N, int K) {
  constexpr int BK = 64;
  constexpr int NW = WM * WN;
  constexpr int T = NW * 64;
  constexpr int WTM = BM / WM, WTN = BN / WN;
  constexpr int FM = WTM / 16, FN = WTN / 16, HM = FM / 2;
  constexpr int AT = BM * BK, BTL = BN * BK;
  constexpr int LA = AT / 8 / T, LB = BTL / 8 / T;
  constexpr int LTOT = LA + LB;
  __shared__ u16 smem[2 * (AT + BTL)];

  int t = threadIdx.x, lane = t & 63, w = t >> 6;
  int wm = w / WN, wn = w % WN;
  int bx, by;
  xcd_swizzle(bx, by);
  const u16* Ag = A + (size_t)(by * BM) * K;
  const u16* Bg = Bt + (size_t)(bx * BN) * K;
  f32x4 acc[FM][FN] = {};

  auto stage = [&](int d, int k0) {
    u16* ab = smem + d * (AT + BTL);
    u16* bb = ab + AT;
#pragma unroll
    for (int l = 0; l < LA; l++) {
      int c = (l * NW + w) * 64 + lane;
      int r = c >> 3, s = c & 7;
      gload16(Ag + (size_t)r * K + k0 + ((s ^ (r & 7)) << 3), ab + (l * NW + w) * 512);
    }
#pragma unroll
    for (int l = 0; l < LB; l++) {
      int c = (l * NW + w) * 64 + lane;
      int r = c >> 3, s = c & 7;
      gload16(Bg + (size_t)r * K + k0 + ((s ^ (r & 7)) << 3), bb + (l * NW + w) * 512);
    }
  };

  auto rdA = [&](const u16* ab, int mi, int ks) {
    int rr = wm * WTM + mi * 16 + (lane & 15);
    int j = ks * 4 + (lane >> 4);
    return *(const short8*)&ab[rr * BK + ((j ^ (rr & 7)) << 3)];
  };
  auto rdB = [&](const u16* bb, int ni, int ks) {
    int rr = wn * WTN + ni * 16 + (lane & 15);
    int j = ks * 4 + (lane >> 4);
    return *(const short8*)&bb[rr * BK + ((j ^ (rr & 7)) << 3)];
  };

  const int NT = K / BK;
  stage(0, 0);
  stage(1, BK);
  __builtin_amdgcn_sched_barrier(0);

  int buf = 0;
  for (int tt = 0; tt < NT; tt++) {
    asm volatile("s_waitcnt vmcnt(%0)" ::"n"(LTOT) : "memory");
    __builtin_amdgcn_s_barrier();
    __builtin_amdgcn_sched_barrier(0);
    const u16* ab = smem + buf * (AT + BTL);
    const u16* bb = ab + AT;
    short8 b0[FN], a0lo[HM], a0hi[HM], b1[FN], a1lo[HM], a1hi[HM];
#pragma unroll
    for (int n = 0; n < FN; n++) b0[n] = rdB(bb, n, 0);
#pragma unroll
    for (int m = 0; m < HM; m++) a0lo[m] = rdA(ab, m, 0);
#pragma unroll
    for (int m = 0; m < HM; m++) a0hi[m] = rdA(ab, HM + m, 0);
    asm volatile("s_waitcnt lgkmcnt(%0)" ::"n"(HM) : "memory");
    __builtin_amdgcn_sched_barrier(0);
#pragma unroll
    for (int n = 0; n < FN; n++) b1[n] = rdB(bb, n, 1);
#pragma unroll
    for (int m = 0; m < HM; m++) a1lo[m] = rdA(ab, m, 1);
    __builtin_amdgcn_s_setprio(1);
#pragma unroll
    for (int m = 0; m < HM; m++)
#pragma unroll
      for (int n = 0; n < FN; n++)
        acc[m][n] = __builtin_amdgcn_mfma_f32_16x16x32_bf16(a0lo[m], b0[n], acc[m][n], 0, 0, 0);
    __builtin_amdgcn_s_setprio(0);
    asm volatile("s_waitcnt lgkmcnt(%0)" ::"n"(FN + HM) : "memory");
    __builtin_amdgcn_sched_barrier(0);
#pragma unroll
    for (int m = 0; m < HM; m++) a1hi[m] = rdA(ab, HM + m, 1);
    __builtin_amdgcn_s_setprio(1);
#pragma unroll
    for (int m = 0; m < HM; m++)
#pragma unroll
      for (int n = 0; n < FN; n++)
        acc[HM + m][n] = __builtin_amdgcn_mfma_f32_16x16x32_bf16(a0hi[m], b0[n], acc[HM + m][n], 0, 0, 0);
    __builtin_amdgcn_s_setprio(0);
    asm volatile("s_waitcnt lgkmcnt(%0)" ::"n"(HM) : "memory");
    __builtin_amdgcn_sched_barrier(0);
    __builtin_amdgcn_s_setprio(1);
#pragma unroll
    for (int m = 0; m < HM; m++)
#pragma unroll
      for (int n = 0; n < FN; n++)
        acc[m][n] = __builtin_amdgcn_mfma_f32_16x16x32_bf16(a1lo[m], b1[n], acc[m][n], 0, 0, 0);
    __builtin_amdgcn_s_setprio(0);
    asm volatile("s_waitcnt lgkmcnt(0)" ::: "memory");
    __builtin_amdgcn_sched_barrier(0);
    __builtin_amdgcn_s_barrier();
    __builtin_amdgcn_sched_barrier(0);
    stage(buf, ((tt + 2) % NT) * BK);
    __builtin_amdgcn_sched_barrier(0);
    __builtin_amdgcn_s_setprio(1);
#pragma unroll
    for (int m = 0; m < HM; m++)
#pragma unroll
      for (int n = 0; n < FN; n++)
        acc[HM + m][n] = __builtin_amdgcn_mfma_f32_16x16x32_bf16(a1hi[m], b1[n], acc[HM + m][n], 0, 0, 0);
    __builtin_amdgcn_s_setprio(0);
    buf ^= 1;
  }

  int r0 = by * BM + wm * WTM + ((lane >> 4) << 2);
  int c0 = bx * BN + wn * WTN + (lane & 15);
#pragma unroll
  for (int mi = 0; mi < FM; mi++) {
#pragma unroll
    for (int r = 0; r < 4; r++) {
      size_t row = (size_t)(r0 + mi * 16 + r);
#pragma unroll
      for (int ni = 0; ni < FN; ni++) {
        size_t col = (size_t)(c0 + ni * 16);
        size_t idx = row * N + col;
        float val = acc[mi][ni][r];
        if (MODE == 0) {
          outb[idx] = f2bf(val);
        } else if (MODE == 1) {
          outf[idx] = val + bias[col] + resid[idx];
        } else {
          outb[idx] = f2bf(gelu_tanh(val + bias[col]));
        }
      }
    }
  }
}

// ---------------- flash attention v3: QBLK=128, 8 waves, V from pre-transposed V^T ----
// (measured-best attention: reg-staged K/V with prefetch-before-compute)
__global__ __launch_bounds__(512, 2) void attn_kernel(const u16* __restrict__ qb,
                                                      const u16* __restrict__ kvb,
                                                      const u16* __restrict__ vtb,
                                                      u16* __restrict__ ob) {
  int qt = blockIdx.x, bh = blockIdx.y;
  int b = bh >> 4, h = bh & 15;
  int t = threadIdx.x, lane = t & 63, w = t >> 6;  // 8 waves
  __shared__ u16 Qs[128 * 64];
  __shared__ u16 Ks[64 * 64];
  __shared__ u16 Vt[64 * 64];
  __shared__ u16 Ps[8][16 * 64];

  const u16* qbase = qb + (size_t)b * N_SEQ * 1024 + h * 64;
  const u16* kbase = kvb + (size_t)b * N_SEQ * 2048 + h * 64;
  const u16* vtbase = vtb + ((size_t)(b * 16 + h) * 64) * 1024;
  u16* obase = ob + (size_t)b * N_SEQ * 1024 + h * 64;

  {  // Q: 128 rows x 64 cols, 2 short8 per thread
    int r = t >> 2, c = (t & 3) * 16;
    const u16* src = qbase + (size_t)(qt * 128 + r) * 1024 + c;
    *(short8*)&Qs[r * 64 + c] = *(const short8*)src;
    *(short8*)&Qs[r * 64 + c + 8] = *(const short8*)(src + 8);
  }
  // K/V prefetch: 64x64 tile, 1 short8 per thread
  int kr = t >> 3, kc = (t & 7) * 8;
  short8 kreg, vreg;
  {
    kreg = *(const short8*)(kbase + (size_t)kr * 2048 + kc);
    vreg = *(const short8*)(vtbase + (size_t)kr * 1024 + kc);
  }
  __syncthreads();
  short8 qa0 = *(const short8*)&Qs[(w * 16 + (lane & 15)) * 64 + (lane >> 4) * 8];
  short8 qa1 = *(const short8*)&Qs[(w * 16 + (lane & 15)) * 64 + 32 + (lane >> 4) * 8];

  f32x4 o[4] = {};
  float m_r[4] = {-1e30f, -1e30f, -1e30f, -1e30f};
  float l_r[4] = {0.0f, 0.0f, 0.0f, 0.0f};

  for (int kt = 0; kt < 16; kt++) {
    if (kt > 0) __syncthreads();
    {
      int jj0 = kc >> 3;  // 0..7
      *(short8*)&Ks[kr * 64 + ((jj0 ^ (kr & 7)) << 3)] = kreg;
      *(short8*)&Vt[kr * 64 + ((jj0 ^ (kr & 7)) << 3)] = vreg;
    }
    __syncthreads();
    if (kt < 15) {
      kreg = *(const short8*)(kbase + (size_t)((kt + 1) * 64 + kr) * 2048 + kc);
      vreg = *(const short8*)(vtbase + (size_t)kr * 1024 + (kt + 1) * 64 + kc);
    }

    f32x4 s[4] = {};
#pragma unroll
    for (int kb = 0; kb < 4; kb++) {
      int key = kb * 16 + (lane & 15);
      int jj = lane >> 4;
      short8 k0 = *(const short8*)&Ks[key * 64 + ((jj ^ (key & 7)) << 3)];
      short8 k1 = *(const short8*)&Ks[key * 64 + (((4 + jj) ^ (key & 7)) << 3)];
      s[kb] = __builtin_amdgcn_mfma_f32_16x16x32_bf16(qa0, k0, s[kb], 0, 0, 0);
      s[kb] = __builtin_amdgcn_mfma_f32_16x16x32_bf16(qa1, k1, s[kb], 0, 0, 0);
    }
    float fac[4], rowsum[4];
#pragma unroll
    for (int rr = 0; rr < 4; rr++) {
      float a = fmaxf(fmaxf(s[0][rr], s[1][rr]), fmaxf(s[2][rr], s[3][rr])) * ATT_SCALE;
      a = fmaxf(a, __shfl_xor(a, 1, 64));
      a = fmaxf(a, __shfl_xor(a, 2, 64));
      a = fmaxf(a, __shfl_xor(a, 4, 64));
      a = fmaxf(a, __shfl_xor(a, 8, 64));
      float mn = fmaxf(m_r[rr], a);
      fac[rr] = __expf(m_r[rr] - mn);
      m_r[rr] = mn;
      rowsum[rr] = 0.0f;
    }
#pragma unroll
    for (int kb = 0; kb < 4; kb++) {
      int chunk = 2 * kb + ((lane & 15) >> 3);
#pragma unroll
      for (int rr = 0; rr < 4; rr++) {
        float p = __expf(s[kb][rr] * ATT_SCALE - m_r[rr]);
        rowsum[rr] += p;
        int row = (lane >> 4) * 4 + rr;
        Ps[w][row * 64 + ((chunk ^ (row & 7)) << 3) + (lane & 7)] = f2bf(p);
      }
    }
#pragma unroll
    for (int rr = 0; rr < 4; rr++) {
      float rs = rowsum[rr];
      rs += __shfl_xor(rs, 1, 64);
      rs += __shfl_xor(rs, 2, 64);
      rs += __shfl_xor(rs, 4, 64);
      rs += __shfl_xor(rs, 8, 64);
      l_r[rr] = l_r[rr] * fac[rr] + rs;
      o[0][rr] *= fac[rr];
      o[1][rr] *= fac[rr];
      o[2][rr] *= fac[rr];
      o[3][rr] *= fac[rr];
    }
#pragma unroll
    for (int ks = 0; ks < 2; ks++) {
      int rowp = lane & 15;
      int jj = 4 * ks + (lane >> 4);
      short8 pf = *(const short8*)&Ps[w][rowp * 64 + ((jj ^ (rowp & 7)) << 3)];
#pragma unroll
      for (int db = 0; db < 4; db++) {
        int row = db * 16 + (lane & 15);
        short8 vf = *(const short8*)&Vt[row * 64 + ((jj ^ (row & 7)) << 3)];
        o[db] = __builtin_amdgcn_mfma_f32_16x16x32_bf16(pf, vf, o[db], 0, 0, 0);
      }
    }
  }
#pragma unroll
  for (int rr = 0; rr < 4; rr++) {
    float inv = 1.0f / l_r[rr];
    size_t row = (size_t)(qt * 128 + w * 16 + (lane >> 4) * 4 + rr);
#pragma unroll
    for (int db = 0; db < 4; db++)
      obase[row * 1024 + db * 16 + (lane & 15)] = f2bf(o[db][rr] * inv);
  }
}

extern "C" void kernel_launch(void* const* d_in, const int* in_sizes, int n_in,
                              void* d_out, int out_size, void* d_ws, size_t ws_size,
                              hipStream_t stream) {
  const float* x1 = (const float*)d_in[0];
  const float* x2 = (const float*)d_in[1];
  const float* ln1_g = (const float*)d_in[2];
  const float* ln1_b = (const float*)d_in[3];
  const float* wq = (const float*)d_in[4];
  const float* wk = (const float*)d_in[5];
  const float* wv = (const float*)d_in[6];
  const float* wo = (const float*)d_in[7];
  const float* bo = (const float*)d_in[8];
  const float* ln2_g = (const float*)d_in[9];
  const float* ln2_b = (const float*)d_in[10];
  const float* w1 = (const float*)d_in[11];
  const float* b1 = (const float*)d_in[12];
  const float* w2 = (const float*)d_in[13];
  const float* b2 = (const float*)d_in[14];
  float* xout = (float*)d_out;

  u16* p = (u16*)d_ws;
  u16* wqt = p;   p += (size_t)6 * 1024 * 1024;
  u16* kvt = p;   p += (size_t)6 * 2048 * 1024;
  u16* wot = p;   p += (size_t)6 * 1024 * 1024;
  u16* w1t = p;   p += (size_t)6 * 4096 * 1024;
  u16* w2t = p;   p += (size_t)6 * 1024 * 4096;
  u16* n1 = p;    p += (size_t)N_TOK * 1024;
  u16* n2all = p; p += (size_t)6 * N_TOK * 1024;  // later reused as vtb6 (same size)
  u16* qbuf = p;  p += (size_t)N_TOK * 1024;
  u16* kvb6 = p;  p += (size_t)6 * N_TOK * 2048;
  u16* ao = p;    p += (size_t)N_TOK * 1024;
  u16* hid = p;   p += (size_t)N_TOK * 4096;
  u16* vtb6 = n2all;  // alias: n2all dead after the KV gemm

  dim3 blk(256);
  tconv_kernel<<<dim3(16, 16, 6), blk, 0, stream>>>(wq, wqt, 1024, 1024, (size_t)1024 * 1024);
  tconv_kernel<<<dim3(16, 16, 6), blk, 0, stream>>>(wk, kvt, 1024, 1024, (size_t)2048 * 1024);
  tconv_kernel<<<dim3(16, 16, 6), blk, 0, stream>>>(wv, kvt + (size_t)1024 * 1024, 1024, 1024, (size_t)2048 * 1024);
  tconv_kernel<<<dim3(16, 16, 6), blk, 0, stream>>>(wo, wot, 1024, 1024, (size_t)1024 * 1024);
  tconv_kernel<<<dim3(64, 16, 6), blk, 0, stream>>>(w1, w1t, 1024, 4096, (size_t)4096 * 1024);
  tconv_kernel<<<dim3(16, 64, 6), blk, 0, stream>>>(w2, w2t, 4096, 1024, (size_t)1024 * 4096);
  copy_f32_kernel<<<4096, blk, 0, stream>>>(x1, xout);

  // x2 layer-invariant: 6 LN upfront, one z-batched KV dispatch, V^T materialization.
  for (int i = 0; i < 6; i++)
    ln_kernel<<<N_TOK, blk, 0, stream>>>(x2, ln1_g + i * 1024, ln1_b + i * 1024,
                                         n2all + (size_t)i * N_TOK * 1024);
  gemmS<64, 128, 2, 2, 3, 0><<<dim3(16, 64, 6), blk, 0, stream>>>(
      n2all, kvt, kvb6, nullptr, nullptr, nullptr, 2048, 1024,
      (size_t)N_TOK * 1024, (size_t)2048 * 1024, (size_t)N_TOK * 2048);
  vtrans_kernel<<<dim3(16, 64, 6), blk, 0, stream>>>(kvb6, vtb6);

  for (int i = 0; i < 6; i++) {
    ln_kernel<<<N_TOK, blk, 0, stream>>>(xout, ln1_g + i * 1024, ln1_b + i * 1024, n1);
    // q: gemm8 128x64, grid 512
    gemm8<128, 64, 2, 2, 0><<<dim3(16, 32), blk, 0, stream>>>(
        n1, wqt + (size_t)i * 1024 * 1024, qbuf, nullptr, nullptr, nullptr, 1024, 1024);
    // attn v3: QBLK=128, grid (8,64), 512 threads
    attn_kernel<<<dim3(8, 64), dim3(512), 0, stream>>>(
        qbuf, kvb6 + (size_t)i * N_TOK * 2048, vtb6 + (size_t)i * 4 * 16 * 64 * 1024, ao);
    // wo + bias + residual
    gemm8<128, 64, 2, 2, 1><<<dim3(16, 32), blk, 0, stream>>>(
        ao, wot + (size_t)i * 1024 * 1024, nullptr, xout, bo + i * 1024, xout, 1024, 1024);
    ln_kernel<<<N_TOK, blk, 0, stream>>>(xout, ln2_g + i * 1024, ln2_b + i * 1024, n1);
    // ff1 + gelu: gemmS 64x128 grid (32,64)=2048
    gemmS<64, 128, 2, 2, 3, 2><<<dim3(32, 64), blk, 0, stream>>>(
        n1, w1t + (size_t)i * 4096 * 1024, hid, nullptr, b1 + i * 4096, nullptr, 4096, 1024, 0, 0, 0);
    // ff2 + bias + residual: gemm8 128x64, K=4096
    gemm8<128, 64, 2, 2, 1><<<dim3(16, 32), blk, 0, stream>>>(
        hid, w2t + (size_t)i * 1024 * 4096, nullptr, xout, b2 + i * 1024, xout, 1024, 4096);
  }
}